// Round 6
// baseline (197.420 us; speedup 1.0000x reference)
//
#include <hip/hip_runtime.h>
#include <hip/hip_bf16.h>
#include <cstdint>
#include <cstddef>

// B=4, T=256, U=64, H=512, K=512, V=1024; M = 65536 rows, log_softmax over V.
// Round 6: BM=32, 512 threads = 8 waves (1M x 8N), acc 64/wave. B read directly
// from L2-resident w2st image, NO register prefetch, NO K-loop unroll ->
// live set ~120 regs -> launch_bounds(512,4) -> 2 blocks/CU (16 waves/CU).
// Latency hidden by TLP, not register pipelining (round-5 lesson: reg
// prefetch halved occupancy and lost more than it gained).

typedef __attribute__((ext_vector_type(8))) short short8;
typedef __attribute__((ext_vector_type(4))) float f32x4;

#define BS_CHUNK 65536                // one BK=32 chunk of W2 image: 1024 cols * 64 B

// ws layout
#define WS_EP_OFF 0                           // 1024*512 f32 = 2 MiB
#define WS_DP_OFF (1024 * 512 * 4)            // 256*512 f32 = 512 KiB
#define WS_W2_OFF (WS_DP_OFF + 256 * 512 * 4) // W2 bf16 image: 16 chunks * 64 KiB

__device__ __forceinline__ unsigned short f2bf(float x) {
  unsigned int u = __builtin_bit_cast(unsigned int, x);
  u += 0x7FFFu + ((u >> 16) & 1u);
  return (unsigned short)(u >> 16);
}

__device__ __forceinline__ float fast_tanh(float x) {
  // tanh(x) = sign(x) * (1-e)/(1+e), e = exp(-2|x|)  -- e<=1, no overflow
  float ax = fabsf(x);
  float e = __expf(-2.0f * ax);
  float t = (1.0f - e) * __builtin_amdgcn_rcpf(1.0f + e);  // rcp: 2 inst vs ~10 for exact div
  return copysignf(t, x);
}

// ---------------------------------------------------------------------------
// prep (fused): blocks 0..159 -> ep/dp projections (8 rows each);
//               blocks 160..191 -> W2 repack to bf16 image:
//   w2st[kc*65536 + v*64 + ki*2] = bf16(W2[kc*32+ki][v])
// ---------------------------------------------------------------------------
__global__ __launch_bounds__(512) void prep(
    const float* __restrict__ enc, const float* __restrict__ dec,
    const float* __restrict__ W1, const float* __restrict__ b1,
    const float* __restrict__ W2,
    float* __restrict__ ep, float* __restrict__ dp, char* __restrict__ w2st) {
  __shared__ float As[8 * 512];
  const int tid = threadIdx.x;
  if (blockIdx.x < 160) {
    const int r0 = blockIdx.x * 8;
    const bool isenc = (r0 < 1024);
    const float* A = isenc ? (enc + (size_t)r0 * 512) : (dec + (size_t)(r0 - 1024) * 512);
    const float* W = isenc ? W1 : (W1 + 512 * 512);
    float* O = isenc ? (ep + (size_t)r0 * 512) : (dp + (size_t)(r0 - 1024) * 512);

    for (int idx = tid; idx < 8 * 512; idx += 512) As[idx] = A[idx];
    __syncthreads();

    const int c = tid;
    float acc[8];
#pragma unroll
    for (int r = 0; r < 8; ++r) acc[r] = 0.0f;
    const float4* As4 = (const float4*)As;
#pragma unroll 2
    for (int k4 = 0; k4 < 128; ++k4) {
      const int kb = k4 * 4;
      float w0 = W[(size_t)(kb + 0) * 512 + c];
      float w1 = W[(size_t)(kb + 1) * 512 + c];
      float w2 = W[(size_t)(kb + 2) * 512 + c];
      float w3 = W[(size_t)(kb + 3) * 512 + c];
#pragma unroll
      for (int r = 0; r < 8; ++r) {
        float4 a = As4[r * 128 + k4];
        acc[r] += a.x * w0 + a.y * w1 + a.z * w2 + a.w * w3;
      }
    }
    const float bias = isenc ? b1[c] : 0.0f;
#pragma unroll
    for (int r = 0; r < 8; ++r) O[(size_t)r * 512 + c] = acc[r] + bias;
  } else {
    const int g = (blockIdx.x - 160) * 512 + tid;  // 0..16383
    const int v = g & 1023;
    const int kc = g >> 10;
    unsigned short vals[32];
#pragma unroll
    for (int ki = 0; ki < 32; ++ki)
      vals[ki] = f2bf(W2[(size_t)(kc * 32 + ki) * 1024 + v]);
    uint4* dst = (uint4*)(w2st + (size_t)kc * BS_CHUNK + (size_t)v * 64);
    const uint4* s = (const uint4*)vals;
    dst[0] = s[0]; dst[1] = s[1]; dst[2] = s[2]; dst[3] = s[3];
  }
}

// ---------------------------------------------------------------------------
// joint: block = 32 rows x V=1024; 512 threads = 8 waves; wave w owns cols
// [w*128, w*128+128) (8 n-frags) x all 32 rows (2 m-frags). acc = 64 f32.
// ---------------------------------------------------------------------------
__global__ __launch_bounds__(512, 4) void joint(
    const float* __restrict__ ep, const float* __restrict__ dp,
    const char* __restrict__ w2st, const float* __restrict__ b2,
    float* __restrict__ out) {
  __shared__ char As[32 * 1024];      // A tile bf16, XOR-swizzled rows
  __shared__ float redM[8 * 32];
  __shared__ float redS[8 * 32];

  const int tid = threadIdx.x;
  const int wave = tid >> 6, lane = tid & 63;
  const int lo = lane & 15, hi = lane >> 4;
  const int m0 = blockIdx.x * 32;
  const int bt = m0 >> 6;                           // b*256 + t
  const int dprow0 = ((bt >> 8) << 6) + (m0 & 63);  // b*64 + u0
  const int nbase = wave * 128;

  // -- phase 1: A[32][512] = tanh(ep+dp) -> bf16 LDS, addr ^ ((row&7)<<4) --
  {
    const int c0 = (tid & 63) * 8;
    const int rb = tid >> 6;          // rows rb, rb+8, rb+16, rb+24
    const float* epr = ep + (size_t)bt * 512 + c0;
    float e0[8];
    *(float4*)(e0) = *(const float4*)(epr);
    *(float4*)(e0 + 4) = *(const float4*)(epr + 4);
#pragma unroll
    for (int p = 0; p < 4; ++p) {
      const int row = rb + p * 8;
      const float* dpr = dp + (size_t)(dprow0 + row) * 512 + c0;
      float d0[8];
      *(float4*)(d0) = *(const float4*)(dpr);
      *(float4*)(d0 + 4) = *(const float4*)(dpr + 4);
      unsigned short h[8];
#pragma unroll
      for (int j = 0; j < 8; ++j) h[j] = f2bf(fast_tanh(e0[j] + d0[j]));
      *(uint4*)(As + ((row * 1024 + c0 * 2) ^ ((row & 7) << 4))) = *(const uint4*)h;
    }
  }

  f32x4 acc[2][8];
#pragma unroll
  for (int mi = 0; mi < 2; ++mi)
#pragma unroll
    for (int ni = 0; ni < 8; ++ni)
#pragma unroll
      for (int j = 0; j < 4; ++j) acc[mi][ni][j] = 0.0f;

  __syncthreads();  // A visible; only barrier before epilogue

  const int axor = (lo & 7) << 4;
  const char* bp0 = w2st + (size_t)(nbase + lo) * 64 + hi * 16;  // ni 0..3 (+ni*1024 imm)
  const char* bp1 = bp0 + 4096;                                  // ni 4..7

  // -- K loop: 16 chunks of BK=32, no unroll, no reg prefetch (TLP hides) --
#pragma unroll 1
  for (int kc = 0; kc < 16; ++kc) {
    short8 b[8];
#pragma unroll
    for (int ni = 0; ni < 4; ++ni) b[ni] = *(const short8*)(bp0 + ni * 1024);
#pragma unroll
    for (int ni = 0; ni < 4; ++ni) b[ni + 4] = *(const short8*)(bp1 + ni * 1024);
    short8 a0 = *(const short8*)(As + ((lo * 1024 + kc * 64 + hi * 16) ^ axor));
    short8 a1 = *(const short8*)(As + (((16 + lo) * 1024 + kc * 64 + hi * 16) ^ axor));
    __builtin_amdgcn_s_setprio(1);
#pragma unroll
    for (int ni = 0; ni < 8; ++ni) {
      acc[0][ni] = __builtin_amdgcn_mfma_f32_16x16x32_bf16(a0, b[ni], acc[0][ni], 0, 0, 0);
      acc[1][ni] = __builtin_amdgcn_mfma_f32_16x16x32_bf16(a1, b[ni], acc[1][ni], 0, 0, 0);
    }
    __builtin_amdgcn_s_setprio(0);
    bp0 += BS_CHUNK;
    bp1 += BS_CHUNK;
  }

  // -- epilogue: +b2, log_softmax over V, store --
  float b2v[8];
#pragma unroll
  for (int ni = 0; ni < 8; ++ni) b2v[ni] = b2[nbase + ni * 16 + lo];
#pragma unroll
  for (int mi = 0; mi < 2; ++mi)
#pragma unroll
    for (int ni = 0; ni < 8; ++ni)
#pragma unroll
      for (int j = 0; j < 4; ++j) acc[mi][ni][j] += b2v[ni];

  float pm[2][4];
#pragma unroll
  for (int mi = 0; mi < 2; ++mi)
#pragma unroll
    for (int r = 0; r < 4; ++r) {
      float m = -3.402823e38f;
#pragma unroll
      for (int ni = 0; ni < 8; ++ni) m = fmaxf(m, acc[mi][ni][r]);
      pm[mi][r] = m;
    }
#pragma unroll
  for (int off = 1; off < 16; off <<= 1)
#pragma unroll
    for (int mi = 0; mi < 2; ++mi)
#pragma unroll
      for (int r = 0; r < 4; ++r)
        pm[mi][r] = fmaxf(pm[mi][r], __shfl_xor(pm[mi][r], off));
  if (lo == 0) {
#pragma unroll
    for (int mi = 0; mi < 2; ++mi)
#pragma unroll
      for (int r = 0; r < 4; ++r)
        redM[wave * 32 + mi * 16 + hi * 4 + r] = pm[mi][r];
  }
  __syncthreads();
  float rm[2][4];
#pragma unroll
  for (int mi = 0; mi < 2; ++mi)
#pragma unroll
    for (int r = 0; r < 4; ++r) {
      const int row = mi * 16 + hi * 4 + r;
      float m = redM[row];
#pragma unroll
      for (int w = 1; w < 8; ++w) m = fmaxf(m, redM[w * 32 + row]);
      rm[mi][r] = m;
    }

  float ps[2][4];
#pragma unroll
  for (int mi = 0; mi < 2; ++mi)
#pragma unroll
    for (int r = 0; r < 4; ++r) {
      float s = 0.0f;
#pragma unroll
      for (int ni = 0; ni < 8; ++ni) s += __expf(acc[mi][ni][r] - rm[mi][r]);
      ps[mi][r] = s;
    }
#pragma unroll
  for (int off = 1; off < 16; off <<= 1)
#pragma unroll
    for (int mi = 0; mi < 2; ++mi)
#pragma unroll
      for (int r = 0; r < 4; ++r)
        ps[mi][r] += __shfl_xor(ps[mi][r], off);
  if (lo == 0) {
#pragma unroll
    for (int mi = 0; mi < 2; ++mi)
#pragma unroll
      for (int r = 0; r < 4; ++r)
        redS[wave * 32 + mi * 16 + hi * 4 + r] = ps[mi][r];
  }
  __syncthreads();

#pragma unroll
  for (int mi = 0; mi < 2; ++mi)
#pragma unroll
    for (int r = 0; r < 4; ++r) {
      const int row = mi * 16 + hi * 4 + r;
      float s = 0.0f;
#pragma unroll
      for (int w = 0; w < 8; ++w) s += redS[w * 32 + row];
      const float sub = rm[mi][r] + __logf(s);
      float* op = out + (size_t)(m0 + row) * 1024 + nbase + lo;
#pragma unroll
      for (int ni = 0; ni < 8; ++ni) op[ni * 16] = acc[mi][ni][r] - sub;
    }
}

// ---------------------------------------------------------------------------
extern "C" void kernel_launch(void* const* d_in, const int* in_sizes, int n_in,
                              void* d_out, int out_size, void* d_ws, size_t ws_size,
                              hipStream_t stream) {
  const float* enc = (const float*)d_in[0];
  const float* dec = (const float*)d_in[1];
  const float* W1  = (const float*)d_in[2];
  const float* b1  = (const float*)d_in[3];
  const float* W2  = (const float*)d_in[4];
  const float* b2  = (const float*)d_in[5];
  float* out = (float*)d_out;

  char* ws = (char*)d_ws;
  float* ep = (float*)(ws + WS_EP_OFF);
  float* dp = (float*)(ws + WS_DP_OFF);
  char* w2st = ws + WS_W2_OFF;

  prep<<<192, 512, 0, stream>>>(enc, dec, W1, b1, W2, ep, dp, w2st);
  joint<<<2048, 512, 0, stream>>>(ep, dp, w2st, b2, out);
}

// Round 7
// 197.192 us; speedup vs baseline: 1.0012x; 1.0012x over previous
//
#include <hip/hip_runtime.h>
#include <hip/hip_bf16.h>
#include <cstdint>
#include <cstddef>

// B=4, T=256, U=64, H=512, K=512, V=1024; M = 65536 rows, log_softmax over V.
// Round 7: round-6 structure (BM=32, 8 waves 1Mx8N, direct-L2 B reads,
// 2 blocks/CU = 16 waves/CU) + K-CHUNK ROTATION: block reads chunks
// (kc + blockIdx&15) & 15. De-synchronizes the chip-wide hot set (was: all
// 256 CUs hammering the same 64KB simultaneously -> L2 queueing latency),
// and co-resident blocks (bid, bid+256: same rot) L1-share their B lines.

typedef __attribute__((ext_vector_type(8))) short short8;
typedef __attribute__((ext_vector_type(4))) float f32x4;

#define BS_CHUNK 65536                // one BK=32 chunk of W2 image: 1024 cols * 64 B

// ws layout
#define WS_EP_OFF 0                           // 1024*512 f32 = 2 MiB
#define WS_DP_OFF (1024 * 512 * 4)            // 256*512 f32 = 512 KiB
#define WS_W2_OFF (WS_DP_OFF + 256 * 512 * 4) // W2 bf16 image: 16 chunks * 64 KiB

__device__ __forceinline__ unsigned short f2bf(float x) {
  unsigned int u = __builtin_bit_cast(unsigned int, x);
  u += 0x7FFFu + ((u >> 16) & 1u);
  return (unsigned short)(u >> 16);
}

__device__ __forceinline__ float fast_tanh(float x) {
  float ax = fabsf(x);
  float e = __expf(-2.0f * ax);
  float t = (1.0f - e) * __builtin_amdgcn_rcpf(1.0f + e);
  return copysignf(t, x);
}

// ---------------------------------------------------------------------------
// prep (fused): blocks 0..159 -> ep/dp projections (8 rows each);
//               blocks 160..191 -> W2 repack to bf16 image:
//   w2st[kc*65536 + v*64 + ki*2] = bf16(W2[kc*32+ki][v])
// ---------------------------------------------------------------------------
__global__ __launch_bounds__(512) void prep(
    const float* __restrict__ enc, const float* __restrict__ dec,
    const float* __restrict__ W1, const float* __restrict__ b1,
    const float* __restrict__ W2,
    float* __restrict__ ep, float* __restrict__ dp, char* __restrict__ w2st) {
  __shared__ float As[8 * 512];
  const int tid = threadIdx.x;
  if (blockIdx.x < 160) {
    const int r0 = blockIdx.x * 8;
    const bool isenc = (r0 < 1024);
    const float* A = isenc ? (enc + (size_t)r0 * 512) : (dec + (size_t)(r0 - 1024) * 512);
    const float* W = isenc ? W1 : (W1 + 512 * 512);
    float* O = isenc ? (ep + (size_t)r0 * 512) : (dp + (size_t)(r0 - 1024) * 512);

    for (int idx = tid; idx < 8 * 512; idx += 512) As[idx] = A[idx];
    __syncthreads();

    const int c = tid;
    float acc[8];
#pragma unroll
    for (int r = 0; r < 8; ++r) acc[r] = 0.0f;
    const float4* As4 = (const float4*)As;
#pragma unroll 2
    for (int k4 = 0; k4 < 128; ++k4) {
      const int kb = k4 * 4;
      float w0 = W[(size_t)(kb + 0) * 512 + c];
      float w1 = W[(size_t)(kb + 1) * 512 + c];
      float w2 = W[(size_t)(kb + 2) * 512 + c];
      float w3 = W[(size_t)(kb + 3) * 512 + c];
#pragma unroll
      for (int r = 0; r < 8; ++r) {
        float4 a = As4[r * 128 + k4];
        acc[r] += a.x * w0 + a.y * w1 + a.z * w2 + a.w * w3;
      }
    }
    const float bias = isenc ? b1[c] : 0.0f;
#pragma unroll
    for (int r = 0; r < 8; ++r) O[(size_t)r * 512 + c] = acc[r] + bias;
  } else {
    const int g = (blockIdx.x - 160) * 512 + tid;  // 0..16383
    const int v = g & 1023;
    const int kc = g >> 10;
    unsigned short vals[32];
#pragma unroll
    for (int ki = 0; ki < 32; ++ki)
      vals[ki] = f2bf(W2[(size_t)(kc * 32 + ki) * 1024 + v]);
    uint4* dst = (uint4*)(w2st + (size_t)kc * BS_CHUNK + (size_t)v * 64);
    const uint4* s = (const uint4*)vals;
    dst[0] = s[0]; dst[1] = s[1]; dst[2] = s[2]; dst[3] = s[3];
  }
}

// ---------------------------------------------------------------------------
// joint: block = 32 rows x V=1024; 512 threads = 8 waves; wave w owns cols
// [w*128, w*128+128) (8 n-frags) x all 32 rows (2 m-frags). acc = 64 f32.
// ---------------------------------------------------------------------------
__global__ __launch_bounds__(512, 4) void joint(
    const float* __restrict__ ep, const float* __restrict__ dp,
    const char* __restrict__ w2st, const float* __restrict__ b2,
    float* __restrict__ out) {
  __shared__ char As[32 * 1024];      // A tile bf16, XOR-swizzled rows
  __shared__ float redM[8 * 32];
  __shared__ float redS[8 * 32];

  const int tid = threadIdx.x;
  const int wave = tid >> 6, lane = tid & 63;
  const int lo = lane & 15, hi = lane >> 4;
  const int m0 = blockIdx.x * 32;
  const int bt = m0 >> 6;                           // b*256 + t
  const int dprow0 = ((bt >> 8) << 6) + (m0 & 63);  // b*64 + u0
  const int nbase = wave * 128;
  const int krot = blockIdx.x & 15;  // K-chunk rotation (bid & bid+256 match)

  // -- phase 1: A[32][512] = tanh(ep+dp) -> bf16 LDS, addr ^ ((row&7)<<4) --
  {
    const int c0 = (tid & 63) * 8;
    const int rb = tid >> 6;          // rows rb, rb+8, rb+16, rb+24
    const float* epr = ep + (size_t)bt * 512 + c0;
    float e0[8];
    *(float4*)(e0) = *(const float4*)(epr);
    *(float4*)(e0 + 4) = *(const float4*)(epr + 4);
#pragma unroll
    for (int p = 0; p < 4; ++p) {
      const int row = rb + p * 8;
      const float* dpr = dp + (size_t)(dprow0 + row) * 512 + c0;
      float d0[8];
      *(float4*)(d0) = *(const float4*)(dpr);
      *(float4*)(d0 + 4) = *(const float4*)(dpr + 4);
      unsigned short h[8];
#pragma unroll
      for (int j = 0; j < 8; ++j) h[j] = f2bf(fast_tanh(e0[j] + d0[j]));
      *(uint4*)(As + ((row * 1024 + c0 * 2) ^ ((row & 7) << 4))) = *(const uint4*)h;
    }
  }

  f32x4 acc[2][8];
#pragma unroll
  for (int mi = 0; mi < 2; ++mi)
#pragma unroll
    for (int ni = 0; ni < 8; ++ni)
#pragma unroll
      for (int j = 0; j < 4; ++j) acc[mi][ni][j] = 0.0f;

  __syncthreads();  // A visible; only barrier before epilogue

  const int axor = (lo & 7) << 4;
  const size_t lane_off = (size_t)(nbase + lo) * 64 + hi * 16;

  // -- K loop: 16 chunks of BK=32, rotated start, no unroll, no prefetch --
#pragma unroll 1
  for (int kc = 0; kc < 16; ++kc) {
    int kci = kc + krot;
    kci = (kci >= 16) ? (kci - 16) : kci;   // (kc + krot) & 15, scalar
    const char* bp = w2st + (size_t)kci * BS_CHUNK + lane_off;
    short8 b[8];
#pragma unroll
    for (int ni = 0; ni < 8; ++ni) b[ni] = *(const short8*)(bp + ni * 1024);
    short8 a0 = *(const short8*)(As + ((lo * 1024 + kci * 64 + hi * 16) ^ axor));
    short8 a1 = *(const short8*)(As + (((16 + lo) * 1024 + kci * 64 + hi * 16) ^ axor));
    __builtin_amdgcn_s_setprio(1);
#pragma unroll
    for (int ni = 0; ni < 8; ++ni) {
      acc[0][ni] = __builtin_amdgcn_mfma_f32_16x16x32_bf16(a0, b[ni], acc[0][ni], 0, 0, 0);
      acc[1][ni] = __builtin_amdgcn_mfma_f32_16x16x32_bf16(a1, b[ni], acc[1][ni], 0, 0, 0);
    }
    __builtin_amdgcn_s_setprio(0);
  }

  // -- epilogue: +b2, log_softmax over V, store --
  float b2v[8];
#pragma unroll
  for (int ni = 0; ni < 8; ++ni) b2v[ni] = b2[nbase + ni * 16 + lo];
#pragma unroll
  for (int mi = 0; mi < 2; ++mi)
#pragma unroll
    for (int ni = 0; ni < 8; ++ni)
#pragma unroll
      for (int j = 0; j < 4; ++j) acc[mi][ni][j] += b2v[ni];

  float pm[2][4];
#pragma unroll
  for (int mi = 0; mi < 2; ++mi)
#pragma unroll
    for (int r = 0; r < 4; ++r) {
      float m = -3.402823e38f;
#pragma unroll
      for (int ni = 0; ni < 8; ++ni) m = fmaxf(m, acc[mi][ni][r]);
      pm[mi][r] = m;
    }
#pragma unroll
  for (int off = 1; off < 16; off <<= 1)
#pragma unroll
    for (int mi = 0; mi < 2; ++mi)
#pragma unroll
      for (int r = 0; r < 4; ++r)
        pm[mi][r] = fmaxf(pm[mi][r], __shfl_xor(pm[mi][r], off));
  if (lo == 0) {
#pragma unroll
    for (int mi = 0; mi < 2; ++mi)
#pragma unroll
      for (int r = 0; r < 4; ++r)
        redM[wave * 32 + mi * 16 + hi * 4 + r] = pm[mi][r];
  }
  __syncthreads();
  float rm[2][4];
#pragma unroll
  for (int mi = 0; mi < 2; ++mi)
#pragma unroll
    for (int r = 0; r < 4; ++r) {
      const int row = mi * 16 + hi * 4 + r;
      float m = redM[row];
#pragma unroll
      for (int w = 1; w < 8; ++w) m = fmaxf(m, redM[w * 32 + row]);
      rm[mi][r] = m;
    }

  float ps[2][4];
#pragma unroll
  for (int mi = 0; mi < 2; ++mi)
#pragma unroll
    for (int r = 0; r < 4; ++r) {
      float s = 0.0f;
#pragma unroll
      for (int ni = 0; ni < 8; ++ni) s += __expf(acc[mi][ni][r] - rm[mi][r]);
      ps[mi][r] = s;
    }
#pragma unroll
  for (int off = 1; off < 16; off <<= 1)
#pragma unroll
    for (int mi = 0; mi < 2; ++mi)
#pragma unroll
      for (int r = 0; r < 4; ++r)
        ps[mi][r] += __shfl_xor(ps[mi][r], off);
  if (lo == 0) {
#pragma unroll
    for (int mi = 0; mi < 2; ++mi)
#pragma unroll
      for (int r = 0; r < 4; ++r)
        redS[wave * 32 + mi * 16 + hi * 4 + r] = ps[mi][r];
  }
  __syncthreads();

#pragma unroll
  for (int mi = 0; mi < 2; ++mi)
#pragma unroll
    for (int r = 0; r < 4; ++r) {
      const int row = mi * 16 + hi * 4 + r;
      float s = 0.0f;
#pragma unroll
      for (int w = 0; w < 8; ++w) s += redS[w * 32 + row];
      const float sub = rm[mi][r] + __logf(s);
      float* op = out + (size_t)(m0 + row) * 1024 + nbase + lo;
#pragma unroll
      for (int ni = 0; ni < 8; ++ni) op[ni * 16] = acc[mi][ni][r] - sub;
    }
}

// ---------------------------------------------------------------------------
extern "C" void kernel_launch(void* const* d_in, const int* in_sizes, int n_in,
                              void* d_out, int out_size, void* d_ws, size_t ws_size,
                              hipStream_t stream) {
  const float* enc = (const float*)d_in[0];
  const float* dec = (const float*)d_in[1];
  const float* W1  = (const float*)d_in[2];
  const float* b1  = (const float*)d_in[3];
  const float* W2  = (const float*)d_in[4];
  const float* b2  = (const float*)d_in[5];
  float* out = (float*)d_out;

  char* ws = (char*)d_ws;
  float* ep = (float*)(ws + WS_EP_OFF);
  float* dp = (float*)(ws + WS_DP_OFF);
  char* w2st = ws + WS_W2_OFF;

  prep<<<192, 512, 0, stream>>>(enc, dec, W1, b1, W2, ep, dp, w2st);
  joint<<<2048, 512, 0, stream>>>(ep, dp, w2st, b2, out);
}

// Round 8
// 190.281 us; speedup vs baseline: 1.0375x; 1.0363x over previous
//
#include <hip/hip_runtime.h>
#include <hip/hip_bf16.h>
#include <cstdint>
#include <cstddef>

// B=4, T=256, U=64, H=512, K=512, V=1024; M = 65536 rows, log_softmax over V.
// Round 8: BM=64 (one (b,t) per block), 1024 threads = 16 waves, wave tile
// 64r x 64c (4m x 4n frags, acc = 64 f32). B direct from L2-resident w2st
// with 1-deep register prefetch; total live ~124 regs -> 4 waves/SIMD at the
// 128-VGPR cap (16 waves/CU). Halves per-CU B traffic vs BM=32 (4 MB/CU,
// 53 B/cy demand < 64 B/cy L2-return path). A in LDS, XOR-swizzled.

typedef __attribute__((ext_vector_type(8))) short short8;
typedef __attribute__((ext_vector_type(4))) float f32x4;

#define BS_CHUNK 65536                // one BK=32 chunk of W2 image: 1024 cols * 64 B

// ws layout
#define WS_EP_OFF 0                           // 1024*512 f32 = 2 MiB
#define WS_DP_OFF (1024 * 512 * 4)            // 256*512 f32 = 512 KiB
#define WS_W2_OFF (WS_DP_OFF + 256 * 512 * 4) // W2 bf16 image: 16 chunks * 64 KiB

// joint LDS: A 64 KiB + redM 4K + redF 256 + redS 4K + redF2 256
#define SMEM_TOTAL (65536 + 4096 + 256 + 4096 + 256)

__device__ __forceinline__ unsigned short f2bf(float x) {
  unsigned int u = __builtin_bit_cast(unsigned int, x);
  u += 0x7FFFu + ((u >> 16) & 1u);
  return (unsigned short)(u >> 16);
}

__device__ __forceinline__ float fast_tanh(float x) {
  float ax = fabsf(x);
  float e = __expf(-2.0f * ax);
  float t = (1.0f - e) * __builtin_amdgcn_rcpf(1.0f + e);
  return copysignf(t, x);
}

// ---------------------------------------------------------------------------
// prep (fused): blocks 0..159 -> ep/dp projections (8 rows each);
//               blocks 160..191 -> W2 repack to bf16 image:
//   w2st[kc*65536 + v*64 + ki*2] = bf16(W2[kc*32+ki][v])
// ---------------------------------------------------------------------------
__global__ __launch_bounds__(512) void prep(
    const float* __restrict__ enc, const float* __restrict__ dec,
    const float* __restrict__ W1, const float* __restrict__ b1,
    const float* __restrict__ W2,
    float* __restrict__ ep, float* __restrict__ dp, char* __restrict__ w2st) {
  __shared__ float As[8 * 512];
  const int tid = threadIdx.x;
  if (blockIdx.x < 160) {
    const int r0 = blockIdx.x * 8;
    const bool isenc = (r0 < 1024);
    const float* A = isenc ? (enc + (size_t)r0 * 512) : (dec + (size_t)(r0 - 1024) * 512);
    const float* W = isenc ? W1 : (W1 + 512 * 512);
    float* O = isenc ? (ep + (size_t)r0 * 512) : (dp + (size_t)(r0 - 1024) * 512);

    for (int idx = tid; idx < 8 * 512; idx += 512) As[idx] = A[idx];
    __syncthreads();

    const int c = tid;
    float acc[8];
#pragma unroll
    for (int r = 0; r < 8; ++r) acc[r] = 0.0f;
    const float4* As4 = (const float4*)As;
#pragma unroll 2
    for (int k4 = 0; k4 < 128; ++k4) {
      const int kb = k4 * 4;
      float w0 = W[(size_t)(kb + 0) * 512 + c];
      float w1 = W[(size_t)(kb + 1) * 512 + c];
      float w2 = W[(size_t)(kb + 2) * 512 + c];
      float w3 = W[(size_t)(kb + 3) * 512 + c];
#pragma unroll
      for (int r = 0; r < 8; ++r) {
        float4 a = As4[r * 128 + k4];
        acc[r] += a.x * w0 + a.y * w1 + a.z * w2 + a.w * w3;
      }
    }
    const float bias = isenc ? b1[c] : 0.0f;
#pragma unroll
    for (int r = 0; r < 8; ++r) O[(size_t)r * 512 + c] = acc[r] + bias;
  } else {
    const int g = (blockIdx.x - 160) * 512 + tid;  // 0..16383
    const int v = g & 1023;
    const int kc = g >> 10;
    unsigned short vals[32];
#pragma unroll
    for (int ki = 0; ki < 32; ++ki)
      vals[ki] = f2bf(W2[(size_t)(kc * 32 + ki) * 1024 + v]);
    uint4* dst = (uint4*)(w2st + (size_t)kc * BS_CHUNK + (size_t)v * 64);
    const uint4* s = (const uint4*)vals;
    dst[0] = s[0]; dst[1] = s[1]; dst[2] = s[2]; dst[3] = s[3];
  }
}

// ---------------------------------------------------------------------------
// joint: block = 64 rows (one (b,t)) x V=1024; 1024 threads = 16 waves.
// Wave w owns all 64 rows x cols [w*64, w*64+64): 4 m-frags x 4 n-frags.
// ---------------------------------------------------------------------------
__global__ __launch_bounds__(1024, 4) void joint(
    const float* __restrict__ ep, const float* __restrict__ dp,
    const char* __restrict__ w2st, const float* __restrict__ b2,
    float* __restrict__ out) {
  extern __shared__ char smem[];
  char* As = smem;                           // [64 rows][1024 B], XOR-swizzled
  float* redM = (float*)(smem + 65536);      // [16 waves][64 rows]
  float* redF = redM + 1024;                 // [64]
  float* redS = redF + 64;                   // [16][64]
  float* redF2 = redS + 1024;                // [64]

  const int tid = threadIdx.x;
  const int wave = tid >> 6, lane = tid & 63;
  const int lo = lane & 15, hi = lane >> 4;
  const int bt = blockIdx.x;                 // one (b,t); m0 = bt*64
  const int m0 = bt * 64;
  const int dprow0 = (bt >> 8) * 64;         // b*64
  const int nbase = wave * 64;
  const int krot = bt & 15;

  const char* bbase = w2st + (size_t)(nbase + lo) * 64 + hi * 16;

  // -- prologue: first chunk's B loads (latency hides under tanh phase) --
  short8 b[4];
  {
    const char* src = bbase + (size_t)krot * BS_CHUNK;
#pragma unroll
    for (int ni = 0; ni < 4; ++ni) b[ni] = *(const short8*)(src + ni * 1024);
  }

  // -- phase 1: A[64][512] = tanh(ep+dp) -> bf16 LDS, addr ^ ((row&7)<<4) --
  {
    const int c0 = (tid & 63) * 8;
    const int rg = tid >> 6;                 // rows rg, rg+16, rg+32, rg+48
    const float* epr = ep + (size_t)bt * 512 + c0;
    float e0[8];
    *(float4*)(e0) = *(const float4*)(epr);
    *(float4*)(e0 + 4) = *(const float4*)(epr + 4);
#pragma unroll
    for (int p = 0; p < 4; ++p) {
      const int row = rg + p * 16;
      const float* dpr = dp + (size_t)(dprow0 + row) * 512 + c0;
      float d0[8];
      *(float4*)(d0) = *(const float4*)(dpr);
      *(float4*)(d0 + 4) = *(const float4*)(dpr + 4);
      unsigned short h[8];
#pragma unroll
      for (int j = 0; j < 8; ++j) h[j] = f2bf(fast_tanh(e0[j] + d0[j]));
      *(uint4*)(As + ((row * 1024 + c0 * 2) ^ ((row & 7) << 4))) = *(const uint4*)h;
    }
  }

  f32x4 acc[4][4];
#pragma unroll
  for (int mi = 0; mi < 4; ++mi)
#pragma unroll
    for (int ni = 0; ni < 4; ++ni)
#pragma unroll
      for (int j = 0; j < 4; ++j) acc[mi][ni][j] = 0.0f;

  __syncthreads();  // A visible; only barrier before epilogue

  // -- K loop: 16 chunks of BK=32, rotated, 1-deep B register prefetch --
#pragma unroll 1
  for (int kc = 0; kc < 16; ++kc) {
    int kci = kc + krot;
    kci = (kci >= 16) ? kci - 16 : kci;
    short8 bn[4];
    if (kc < 15) {
      int kn = kci + 1;
      kn = (kn >= 16) ? 0 : kn;
      const char* src = bbase + (size_t)kn * BS_CHUNK;
#pragma unroll
      for (int ni = 0; ni < 4; ++ni) bn[ni] = *(const short8*)(src + ni * 1024);
    }
    short8 a[4];
#pragma unroll
    for (int mi = 0; mi < 4; ++mi) {
      const int row = mi * 16 + lo;
      a[mi] = *(const short8*)(As + ((row * 1024 + kci * 64 + hi * 16) ^ ((row & 7) << 4)));
    }
    __builtin_amdgcn_s_setprio(1);
#pragma unroll
    for (int ni = 0; ni < 4; ++ni)
#pragma unroll
      for (int mi = 0; mi < 4; ++mi)
        acc[mi][ni] = __builtin_amdgcn_mfma_f32_16x16x32_bf16(a[mi], b[ni], acc[mi][ni], 0, 0, 0);
    __builtin_amdgcn_s_setprio(0);
    if (kc < 15) {
#pragma unroll
      for (int ni = 0; ni < 4; ++ni) b[ni] = bn[ni];
    }
  }

  // -- epilogue: +b2, log_softmax over V, store --
  float b2v[4];
#pragma unroll
  for (int ni = 0; ni < 4; ++ni) b2v[ni] = b2[nbase + ni * 16 + lo];
#pragma unroll
  for (int mi = 0; mi < 4; ++mi)
#pragma unroll
    for (int ni = 0; ni < 4; ++ni)
#pragma unroll
      for (int j = 0; j < 4; ++j) acc[mi][ni][j] += b2v[ni];

  // per-thread max over 4 cols per held row, then 16-lane (lo) reduce
  float pm[4][4];
#pragma unroll
  for (int mi = 0; mi < 4; ++mi)
#pragma unroll
    for (int r = 0; r < 4; ++r) {
      float m = fmaxf(fmaxf(acc[mi][0][r], acc[mi][1][r]),
                      fmaxf(acc[mi][2][r], acc[mi][3][r]));
      pm[mi][r] = m;
    }
#pragma unroll
  for (int off = 1; off < 16; off <<= 1)
#pragma unroll
    for (int mi = 0; mi < 4; ++mi)
#pragma unroll
      for (int r = 0; r < 4; ++r)
        pm[mi][r] = fmaxf(pm[mi][r], __shfl_xor(pm[mi][r], off));
  if (lo == 0) {
#pragma unroll
    for (int mi = 0; mi < 4; ++mi)
#pragma unroll
      for (int r = 0; r < 4; ++r)
        redM[wave * 64 + mi * 16 + hi * 4 + r] = pm[mi][r];
  }
  __syncthreads();
  // cross-wave max: row tr = tid>>4 (4 rows/wave), w = lane&15 in-wave
  {
    const int tr = tid >> 4, w = tid & 15;
    float v = redM[w * 64 + tr];
#pragma unroll
    for (int off = 1; off < 16; off <<= 1) v = fmaxf(v, __shfl_xor(v, off));
    if (w == 0) redF[tr] = v;
  }
  __syncthreads();
  float rm[4][4];
#pragma unroll
  for (int mi = 0; mi < 4; ++mi)
#pragma unroll
    for (int r = 0; r < 4; ++r) rm[mi][r] = redF[mi * 16 + hi * 4 + r];

  float ps[4][4];
#pragma unroll
  for (int mi = 0; mi < 4; ++mi)
#pragma unroll
    for (int r = 0; r < 4; ++r) {
      float s = 0.0f;
#pragma unroll
      for (int ni = 0; ni < 4; ++ni) s += __expf(acc[mi][ni][r] - rm[mi][r]);
      ps[mi][r] = s;
    }
#pragma unroll
  for (int off = 1; off < 16; off <<= 1)
#pragma unroll
    for (int mi = 0; mi < 4; ++mi)
#pragma unroll
      for (int r = 0; r < 4; ++r)
        ps[mi][r] += __shfl_xor(ps[mi][r], off);
  if (lo == 0) {
#pragma unroll
    for (int mi = 0; mi < 4; ++mi)
#pragma unroll
      for (int r = 0; r < 4; ++r)
        redS[wave * 64 + mi * 16 + hi * 4 + r] = ps[mi][r];
  }
  __syncthreads();
  {
    const int tr = tid >> 4, w = tid & 15;
    float v = redS[w * 64 + tr];
#pragma unroll
    for (int off = 1; off < 16; off <<= 1) v += __shfl_xor(v, off);
    if (w == 0) redF2[tr] = v;
  }
  __syncthreads();

#pragma unroll
  for (int mi = 0; mi < 4; ++mi)
#pragma unroll
    for (int r = 0; r < 4; ++r) {
      const int row = mi * 16 + hi * 4 + r;
      const float sub = rm[mi][r] + __logf(redF2[row]);
      float* op = out + (size_t)(m0 + row) * 1024 + nbase + lo;
#pragma unroll
      for (int ni = 0; ni < 4; ++ni) op[ni * 16] = acc[mi][ni][r] - sub;
    }
}

// ---------------------------------------------------------------------------
extern "C" void kernel_launch(void* const* d_in, const int* in_sizes, int n_in,
                              void* d_out, int out_size, void* d_ws, size_t ws_size,
                              hipStream_t stream) {
  const float* enc = (const float*)d_in[0];
  const float* dec = (const float*)d_in[1];
  const float* W1  = (const float*)d_in[2];
  const float* b1  = (const float*)d_in[3];
  const float* W2  = (const float*)d_in[4];
  const float* b2  = (const float*)d_in[5];
  float* out = (float*)d_out;

  char* ws = (char*)d_ws;
  float* ep = (float*)(ws + WS_EP_OFF);
  float* dp = (float*)(ws + WS_DP_OFF);
  char* w2st = ws + WS_W2_OFF;

  prep<<<192, 512, 0, stream>>>(enc, dec, W1, b1, W2, ep, dp, w2st);
  joint<<<1024, 1024, SMEM_TOTAL, stream>>>(ep, dp, w2st, b2, out);
}